// Round 8
// baseline (955.215 us; speedup 1.0000x reference)
//
#include <hip/hip_runtime.h>
#include <stdint.h>

// LSTM B=256,T=2048,D=U=64 fp32. 256 WGs (1 batch) x 512 thr (8 waves).
// R7 lesson: 8x ds_read_b128 broadcast per wave/step (VGPR-return BW,
// ~640 cyc/CU/step LDS pipe) + shfl_xor lgkm chain (~240 cyc) were the wall.
// R8: (1) operand delivery via 1x ds_read_b32 + 32x v_readlane -> SGPR,
// dot2 sources the SGPR (LDS pipe ~dead). (2) consumer lane = i*4+q so the
// 4 gates of a unit are one quad: gate exchange = 4x mov_dpp quad_perm
// broadcasts (pure VALU). (3) sXZ stored unit-major (word u*4+q) so the
// consumer combine read is lane-linear conflict-free.
// Waves 0-3 consumers (h.Wh recurrence), waves 4-7 producers (xz = x.Wx + b
// one 16-step chunk ahead, LDS ping-pong). One lgkm-only barrier per step.

#define T_STEPS 2048
#define DIM     64
#define GATES   256
#define CHUNK   16
#define NCHUNK  (T_STEPS / CHUNK)

typedef _Float16 f16;
typedef _Float16 f16x2 __attribute__((ext_vector_type(2)));

__device__ __forceinline__ float fdot2u(uint32_t a, uint32_t b, float acc) {
    return __builtin_amdgcn_fdot2(__builtin_bit_cast(f16x2, a),
                                  __builtin_bit_cast(f16x2, b), acc, false);
}

__device__ __forceinline__ uint32_t packh(float lo, float hi) {
    f16x2 v; v.x = (f16)lo; v.y = (f16)hi;
    return __builtin_bit_cast(uint32_t, v);
}

// Barrier ordering LDS only — never drains vmcnt (stores/loads stay in flight)
__device__ __forceinline__ void sync_lds() {
    __builtin_amdgcn_sched_barrier(0);
    asm volatile("s_waitcnt lgkmcnt(0)" ::: "memory");
    __builtin_amdgcn_sched_barrier(0);
    __builtin_amdgcn_s_barrier();
    __builtin_amdgcn_sched_barrier(0);
}

// 64-dim f16 dot: lanes 0..31 of `word` hold the 32 f16x2 of the vector.
// Broadcast via readlane->SGPR, accumulate in 4 f32 chains.
__device__ __forceinline__ float dot64(const uint32_t* __restrict__ w,
                                       uint32_t word, float a0) {
    float a1 = 0.f, a2 = 0.f, a3 = 0.f;
#pragma unroll
    for (int k = 0; k < 32; k += 4) {
        uint32_t s0 = (uint32_t)__builtin_amdgcn_readlane((int)word, k + 0);
        uint32_t s1 = (uint32_t)__builtin_amdgcn_readlane((int)word, k + 1);
        uint32_t s2 = (uint32_t)__builtin_amdgcn_readlane((int)word, k + 2);
        uint32_t s3 = (uint32_t)__builtin_amdgcn_readlane((int)word, k + 3);
        a0 = fdot2u(w[k + 0], s0, a0);
        a1 = fdot2u(w[k + 1], s1, a1);
        a2 = fdot2u(w[k + 2], s2, a2);
        a3 = fdot2u(w[k + 3], s3, a3);
    }
    return (a0 + a1) + (a2 + a3);
}

__global__ __launch_bounds__(512, 2)
void lstm_dpp_kernel(const float* __restrict__ x,
                     const float* __restrict__ Wx,
                     const float* __restrict__ Wh,
                     const float* __restrict__ bias,
                     float* __restrict__ out)
{
    __shared__ float    sXZ[2][CHUNK][GATES];     // 32 KB, word idx = u*4+q
    __shared__ uint32_t sX [2][CHUNK * 32];       // 8 KB, x chunks f16x2 rows
    __shared__ uint32_t sH [2][32];               // h as 32 f16x2, dbuf

    const int tid = threadIdx.x;
    const int batch = blockIdx.x;
    const float* xb = x + (size_t)batch * T_STEPS * DIM;
    float* ob = out + (size_t)batch * T_STEPS * (2 * DIM);

    const int lane = tid & 63;
    const int wv   = (tid >> 6) & 3;      // wave index within half
    const bool consumer = (tid < 256);
    const int q = lane & 3;               // gate 0=i 1=f 2=g 3=o (consumer)
    const int i = lane >> 2;              // unit-within-wave (consumer)
    const int u = wv * 16 + i;            // unit (consumer)
    // consumer col: gate-major q*64+u; producer col: tid&255
    const int wcol = consumer ? (q * 64 + u) : (tid & 255);

    // ---- weight column as 32 f16x2 registers ----
    const float* Wsrc = consumer ? Wh : Wx;
    uint32_t w[32];
#pragma unroll
    for (int jj = 0; jj < 32; ++jj)
        w[jj] = packh(Wsrc[(2 * jj) * GATES + wcol],
                      Wsrc[(2 * jj + 1) * GATES + wcol]);
#pragma unroll
    for (int jj = 0; jj < 32; ++jj) asm volatile("" : "+v"(w[jj]));
    const float bc = bias[wcol];          // producers fold it into xz

    // ---- prologue ----
    if (tid < 32) { sH[0][tid] = 0u; sH[1][tid] = 0u; }
    if (!consumer) {                      // stage x chunks 0,1 (f16)
        const int p = tid - 256;
#pragma unroll
        for (int j = 0; j < 8; ++j) {
            int v = p + 256 * j;          // flat f16 idx into first 2 chunks
            ((f16*)sX[v >> 10])[v & 1023] = (f16)xb[v];
        }
    }
    __syncthreads();
    const int xzw = ((wcol & 63) << 2) | (wcol >> 6);   // producer xz slot
    if (!consumer) {                      // xz chunk 0
#pragma unroll 1
        for (int s2 = 0; s2 < CHUNK; ++s2) {
            uint32_t word = sX[0][s2 * 32 + (lane & 31)];
            sXZ[0][s2][xzw] = dot64(w, word, bc);
        }
    }
    __syncthreads();

    if (consumer) {
        // ============================ CONSUMER ============================
        float c = 0.f;
#pragma unroll 1
        for (int t = 0; t < T_STEPS; ++t) {
            const int p  = t & 1;
            const int cb = (t >> 4) & 1;
            const int s  = t & 15;
            uint32_t hword = sH[p][lane & 31];            // broadcast pairs
            float zx = sXZ[cb][s][wv * 64 + lane];        // lane-linear
            float z = dot64(w, hword, zx);
            // act: tanh(z) = 2*sigmoid(2z)-1 (single exp path, inf-safe)
            float zz  = (q == 2) ? (z + z) : z;
            float e   = __expf(-zz);
            float sg  = 1.0f / (1.0f + e);
            float act = (q == 2) ? fmaf(2.f, sg, -1.f) : sg;
            // quad gate exchange: lane j of quad holds gate j of unit i
            int ai = __float_as_int(act);
            float gI = __int_as_float(__builtin_amdgcn_mov_dpp(ai, 0x00, 0xf, 0xf, true));
            float gF = __int_as_float(__builtin_amdgcn_mov_dpp(ai, 0x55, 0xf, 0xf, true));
            float gG = __int_as_float(__builtin_amdgcn_mov_dpp(ai, 0xAA, 0xf, 0xf, true));
            float gO = __int_as_float(__builtin_amdgcn_mov_dpp(ai, 0xFF, 0xf, 0xf, true));
            c = fmaf(gF, c, gI * gG);
            float ac = fabsf(c);
            float e2 = __expf(-2.f * ac);
            float th = copysignf((1.f - e2) / (1.f + e2), c);
            float h  = gO * th;
            if (q == 0)      ob[(size_t)t * 128 + u]      = c;   // cell
            else if (q == 1) ob[(size_t)t * 128 + 64 + u] = h;   // hidden
            else if (q == 2) ((f16*)sH[p ^ 1])[u] = (f16)h;      // next h
            sync_lds();
        }
    } else {
        // ============================ PRODUCER ============================
        const int pidx = tid - 256;
        float xs0 = 0.f, xs1 = 0.f, xs2 = 0.f, xs3 = 0.f;
#pragma unroll 1
        for (int t = 0; t < T_STEPS; ++t) {
            const int n = t >> 4;
            const int s = t & 15;
            if (n + 1 < NCHUNK) {           // xz row for chunk n+1, step s
                const int nb = (n + 1) & 1;
                uint32_t word = sX[nb][s * 32 + (lane & 31)];
                sXZ[nb][s][xzw] = dot64(w, word, bc);
            }
            if (n + 2 < NCHUNK) {           // stage x for chunk n+2
                const float* xsrc = xb + (size_t)(n + 2) * CHUNK * DIM;
                if (s == 0) {               // issue loads (latency hidden)
                    xs0 = xsrc[pidx];
                    xs1 = xsrc[pidx + 256];
                    xs2 = xsrc[pidx + 512];
                    xs3 = xsrc[pidx + 768];
                }
                if (s == 8) {               // write f16 half a chunk later
                    f16* dst = (f16*)sX[n & 1];
                    dst[pidx]       = (f16)xs0;
                    dst[pidx + 256] = (f16)xs1;
                    dst[pidx + 512] = (f16)xs2;
                    dst[pidx + 768] = (f16)xs3;
                }
            }
            sync_lds();
        }
    }
}

extern "C" void kernel_launch(void* const* d_in, const int* in_sizes, int n_in,
                              void* d_out, int out_size, void* d_ws, size_t ws_size,
                              hipStream_t stream) {
    const float* x  = (const float*)d_in[0];
    const float* Wx = (const float*)d_in[1];
    const float* Wh = (const float*)d_in[2];
    const float* b  = (const float*)d_in[3];
    float* out = (float*)d_out;

    hipLaunchKernelGGL(lstm_dpp_kernel, dim3(256), dim3(512), 0, stream,
                       x, Wx, Wh, b, out);
}

// Round 9
// 605.441 us; speedup vs baseline: 1.5777x; 1.5777x over previous
//
#include <hip/hip_runtime.h>
#include <stdint.h>

// LSTM B=256,T=2048,D=U=64 fp32. 256 WGs (1 batch) x 256 thr (4 waves).
// R1-R8 lesson: any VALU-based dot costs >=64 VALU-cyc/wave/step -> ~900us
// wall. R9: dots on the (idle) MATRIX pipe via mfma_f32_16x16x32_f16.
// Wave w owns units w*16..+16, all 4 gates = 4 N-tiles (col q*64+w*16+j).
// Per 16-step chunk: acc[q] = bias + X_chunk @ Wx (8 MFMA, D-rows = ts).
// Per step s: h placed in A-row s (zero elsewhere) -> mfma adds h@Wh into
// row s only; rows>s keep xz for future steps. z appears at reg s&3,
// lane-group s>>2: no gate exchange, no xz LDS. c migrates groups via
// ds_bpermute every 4 steps. k-map f(g,e)=g*8+e used for BOTH A and B ->
// result invariant to the true hw k-permutation. C/D layout = m89-verified
// (col=lane&15, row=(lane>>4)*4+reg).

#define T_STEPS 2048
#define DIM     64
#define GATES   256
#define CHUNK   16
#define NCHUNK  (T_STEPS / CHUNK)

typedef _Float16 f16;
typedef _Float16 f16x8 __attribute__((ext_vector_type(8)));
typedef float    f32x4 __attribute__((ext_vector_type(4)));

__device__ __forceinline__ void sync_lds() {
    __builtin_amdgcn_sched_barrier(0);
    asm volatile("s_waitcnt lgkmcnt(0)" ::: "memory");
    __builtin_amdgcn_sched_barrier(0);
    __builtin_amdgcn_s_barrier();
    __builtin_amdgcn_sched_barrier(0);
}

__device__ __forceinline__ float sigm(float z) {
    return __builtin_amdgcn_rcpf(1.f + __expf(-z));
}

#define MFMA16(A, B, C) __builtin_amdgcn_mfma_f32_16x16x32_f16(A, B, C, 0, 0, 0)

__global__ __launch_bounds__(256, 1)
void lstm_mfma_kernel(const float* __restrict__ x,
                      const float* __restrict__ Wx,
                      const float* __restrict__ Wh,
                      const float* __restrict__ bias,
                      float* __restrict__ out)
{
    // sPool: [0:64) h buf0 | [64:128) h buf1 | [128:192) zeros (A rows != s)
    __shared__ __align__(16) f16 sPool[192];

    const int tid  = threadIdx.x;
    const int lane = tid & 63;
    const int w    = tid >> 6;       // wave 0..3 -> units w*16..+16
    const int j    = lane & 15;      // row (A) / col-in-tile (B,D)
    const int g    = lane >> 4;      // k-group: k = g*8 + e (+32 for kstep 1)
    const int u    = w * 16 + j;     // unit

    const int batch = blockIdx.x;
    const float* xb = x + (size_t)batch * T_STEPS * DIM;
    float* ob = out + (size_t)batch * T_STEPS * (2 * DIM);

    // ---- persistent B fragments: col = q*64 + u, k = ks*32 + g*8 + e ----
    f16x8 Bh[4][2], Bx[4][2];
    float bq[4];
#pragma unroll
    for (int q = 0; q < 4; ++q) {
        const int col = q * 64 + u;
        bq[q] = bias[col];
#pragma unroll
        for (int ks = 0; ks < 2; ++ks)
#pragma unroll
            for (int e = 0; e < 8; ++e) {
                const int k = ks * 32 + g * 8 + e;
                Bh[q][ks][e] = (f16)Wh[k * GATES + col];
                Bx[q][ks][e] = (f16)Wx[k * GATES + col];
            }
    }

    if (tid < 192) sPool[tid] = (f16)0.f;

    // bpermute byte-addrs: group migration (g-1 -> g) and chunk wrap (3 -> 0)
    const int addrMig  = ((lane - 16) & 63) * 4;
    const int addrWrap = ((lane + 48) & 63) * 4;

    // ---- chunk 0 A(x) fragments: A[row=ts=j][k=feat], feats g*8.. ----
    f16x8 ax0, ax1;
    {
        const float* xr = xb + (size_t)j * DIM + g * 8;
        float4 x0 = *(const float4*)(xr);
        float4 x1 = *(const float4*)(xr + 4);
        float4 x2 = *(const float4*)(xr + 32);
        float4 x3 = *(const float4*)(xr + 36);
        ax0[0]=(f16)x0.x; ax0[1]=(f16)x0.y; ax0[2]=(f16)x0.z; ax0[3]=(f16)x0.w;
        ax0[4]=(f16)x1.x; ax0[5]=(f16)x1.y; ax0[6]=(f16)x1.z; ax0[7]=(f16)x1.w;
        ax1[0]=(f16)x2.x; ax1[1]=(f16)x2.y; ax1[2]=(f16)x2.z; ax1[3]=(f16)x2.w;
        ax1[4]=(f16)x3.x; ax1[5]=(f16)x3.y; ax1[6]=(f16)x3.z; ax1[7]=(f16)x3.w;
    }

    float c = 0.f;
    __syncthreads();

#define STEP(s) do {                                                         \
        const int aidx = (j == (s)) ? (((s) & 1) * 64 + g * 8) : 128;        \
        f16x8 A0 = *(const f16x8*)&sPool[aidx];                              \
        f16x8 A1 = *(const f16x8*)&sPool[aidx + 32];                         \
        acc0 = MFMA16(A0, Bh[0][0], acc0); acc0 = MFMA16(A1, Bh[0][1], acc0);\
        acc1 = MFMA16(A0, Bh[1][0], acc1); acc1 = MFMA16(A1, Bh[1][1], acc1);\
        acc2 = MFMA16(A0, Bh[2][0], acc2); acc2 = MFMA16(A1, Bh[2][1], acc2);\
        acc3 = MFMA16(A0, Bh[3][0], acc3); acc3 = MFMA16(A1, Bh[3][1], acc3);\
        float zi = acc0[(s) & 3], zf = acc1[(s) & 3];                        \
        float zg = acc2[(s) & 3], zo = acc3[(s) & 3];                        \
        float gi = sigm(zi), gf = sigm(zf), go = sigm(zo);                   \
        float gg = fmaf(2.f, sigm(zg + zg), -1.f);                           \
        if ((s) > 0 && ((s) & 3) == 0)                                       \
            c = __int_as_float(__builtin_amdgcn_ds_bpermute(                 \
                    addrMig, __float_as_int(c)));                            \
        c = fmaf(gf, c, gi * gg);                                            \
        float e2 = __expf(-2.f * fabsf(c));                                  \
        float th = copysignf(                                                \
            fmaf(-2.f, e2 * __builtin_amdgcn_rcpf(1.f + e2), 1.f), c);       \
        float hh = go * th;                                                  \
        if ((lane >> 4) == ((s) >> 2)) {                                     \
            sPool[(((s) + 1) & 1) * 64 + u] = (f16)hh;                       \
            const size_t t = (size_t)n * 16 + (s);                           \
            ob[t * 128 + u] = c;                                             \
            ob[t * 128 + 64 + u] = hh;                                       \
        }                                                                    \
        sync_lds();                                                          \
    } while (0)

#pragma unroll 1
    for (int n = 0; n < NCHUNK; ++n) {
        // xz for this chunk: acc[q] = bias + X_chunk @ Wx (rows = 16 ts)
        f32x4 acc0 = {bq[0], bq[0], bq[0], bq[0]};
        f32x4 acc1 = {bq[1], bq[1], bq[1], bq[1]};
        f32x4 acc2 = {bq[2], bq[2], bq[2], bq[2]};
        f32x4 acc3 = {bq[3], bq[3], bq[3], bq[3]};
        acc0 = MFMA16(ax0, Bx[0][0], acc0); acc0 = MFMA16(ax1, Bx[0][1], acc0);
        acc1 = MFMA16(ax0, Bx[1][0], acc1); acc1 = MFMA16(ax1, Bx[1][1], acc1);
        acc2 = MFMA16(ax0, Bx[2][0], acc2); acc2 = MFMA16(ax1, Bx[2][1], acc2);
        acc3 = MFMA16(ax0, Bx[3][0], acc3); acc3 = MFMA16(ax1, Bx[3][1], acc3);

        // prefetch next chunk's x (lands during the 16 steps below)
        const bool more = (n + 1 < NCHUNK);
        float4 x0, x1, x2, x3;
        if (more) {
            const float* xr = xb + ((size_t)(n + 1) * CHUNK + j) * DIM + g * 8;
            x0 = *(const float4*)(xr);
            x1 = *(const float4*)(xr + 4);
            x2 = *(const float4*)(xr + 32);
            x3 = *(const float4*)(xr + 36);
        }

        STEP(0);  STEP(1);  STEP(2);  STEP(3);
        STEP(4);  STEP(5);  STEP(6);  STEP(7);
        STEP(8);  STEP(9);  STEP(10); STEP(11);
        STEP(12); STEP(13); STEP(14); STEP(15);

        if (more) {
            ax0[0]=(f16)x0.x; ax0[1]=(f16)x0.y; ax0[2]=(f16)x0.z; ax0[3]=(f16)x0.w;
            ax0[4]=(f16)x1.x; ax0[5]=(f16)x1.y; ax0[6]=(f16)x1.z; ax0[7]=(f16)x1.w;
            ax1[0]=(f16)x2.x; ax1[1]=(f16)x2.y; ax1[2]=(f16)x2.z; ax1[3]=(f16)x2.w;
            ax1[4]=(f16)x3.x; ax1[5]=(f16)x3.y; ax1[6]=(f16)x3.z; ax1[7]=(f16)x3.w;
        }
        // chunk wrap: c moves lane-group 3 -> 0
        c = __int_as_float(__builtin_amdgcn_ds_bpermute(addrWrap,
                                                        __float_as_int(c)));
    }
}

extern "C" void kernel_launch(void* const* d_in, const int* in_sizes, int n_in,
                              void* d_out, int out_size, void* d_ws, size_t ws_size,
                              hipStream_t stream) {
    const float* x  = (const float*)d_in[0];
    const float* Wx = (const float*)d_in[1];
    const float* Wh = (const float*)d_in[2];
    const float* b  = (const float*)d_in[3];
    float* out = (float*)d_out;

    hipLaunchKernelGGL(lstm_mfma_kernel, dim3(256), dim3(256), 0, stream,
                       x, Wx, Wh, b, out);
}